// Round 19
// baseline (133.851 us; speedup 1.0000x reference)
//
#include <hip/hip_runtime.h>
#include <stdint.h>

typedef unsigned short u16;
typedef unsigned int   u32;
typedef __attribute__((ext_vector_type(4))) float f32x4;
typedef __attribute__((ext_vector_type(8))) short s16x8;
typedef __attribute__((ext_vector_type(2))) u32 u32x2;
typedef __attribute__((ext_vector_type(4))) u32 u32x4;

__device__ __forceinline__ u16 f2bf(float f) {
  u32 u = __builtin_bit_cast(u32, f);
  u = (u + 0x7FFFu + ((u >> 16) & 1u)) >> 16;
  return (u16)u;
}

__device__ __forceinline__ u32 cvt_pk_bf16(float lo, float hi) {
  u32 r;
  asm("v_cvt_pk_bf16_f32 %0, %1, %2" : "=v"(r) : "v"(lo), "v"(hi));
  return r;
}

__device__ __forceinline__ float exp2_f(float x) {
  float r;
  asm("v_exp_f32 %0, %1" : "=v"(r) : "v"(x));
  return r;
}

__device__ __forceinline__ void gload_lds16(const void* g, void* l) {
  __builtin_amdgcn_global_load_lds((const __attribute__((address_space(1))) void*)g,
                                   (__attribute__((address_space(3))) void*)l,
                                   16, 0, 0);
}

#define MFMA16(a, b, c) __builtin_amdgcn_mfma_f32_16x16x32_bf16((a), (b), (c), 0, 0, 0)

#define INVLN2 1.44269504f
#define SC_X_INVLN2 0.18033688f  /* 0.125 * log2(e) */

// ---------------- transpose+cast weights: W[K][N] fp32 -> Wt[N][K] bf16 ----------------
__global__ void k_transpose_w(const float* __restrict__ w0, const float* __restrict__ w1,
                              const float* __restrict__ w2, const float* __restrict__ w3,
                              u16* __restrict__ o0, u16* __restrict__ o1,
                              u16* __restrict__ o2, u16* __restrict__ o3) {
  __shared__ float t[64][65];
  const int z = blockIdx.z;
  const float* w = (z == 0) ? w0 : (z == 1) ? w1 : (z == 2) ? w2 : w3;
  u16* o = (z == 0) ? o0 : (z == 1) ? o1 : (z == 2) ? o2 : o3;
  const int k0 = blockIdx.x * 64;
  const int n0 = blockIdx.y * 64;
  const int tx = threadIdx.x & 63, ty = threadIdx.x >> 6;
#pragma unroll
  for (int i = 0; i < 16; ++i) {
    const int r = ty * 16 + i;
    t[r][tx] = w[(size_t)(k0 + r) * 1024 + n0 + tx];
  }
  __syncthreads();
#pragma unroll
  for (int i = 0; i < 16; ++i) {
    const int r = ty * 16 + i;
    o[(size_t)(n0 + r) * 1024 + k0 + tx] = f2bf(t[tx][r]);
  }
}

// ---------------- position-bias MLP v2 (exp2-domain output) ----------------
__global__ __launch_bounds__(256) void k_posbias(
    const float* __restrict__ w0, const float* __restrict__ b0,
    const float* __restrict__ w1, const float* __restrict__ b1,
    const float* __restrict__ w2, const float* __restrict__ b2,
    float* __restrict__ tbl) {
  __shared__ float h0[4][264];
  __shared__ float h1[4][264];
  __shared__ float pr[4][4][16];
  const int t = threadIdx.x;
  const int p0 = blockIdx.x * 4;
  {
    const float wy = w0[t], wx = w0[256 + t], bb = b0[t];
#pragma unroll
    for (int r = 0; r < 4; ++r) {
      int p = p0 + r; if (p > 3968) p = 3968;
      const float dy = (float)(p / 63 - 31);
      const float dx = (float)(p % 63 - 31);
      const float v = dy * wy + dx * wx + bb;
      h0[r][t] = v > 0.f ? v : 0.01f * v;
    }
  }
  __syncthreads();
  {
    const float bb = b1[t];
    float a0 = bb, a1 = bb, a2 = bb, a3 = bb;
    for (int k = 0; k < 256; k += 4) {
      const float wA = w1[(k + 0) * 256 + t];
      const float wB = w1[(k + 1) * 256 + t];
      const float wC = w1[(k + 2) * 256 + t];
      const float wD = w1[(k + 3) * 256 + t];
      const float4 x0 = *(const float4*)&h0[0][k];
      const float4 x1 = *(const float4*)&h0[1][k];
      const float4 x2 = *(const float4*)&h0[2][k];
      const float4 x3 = *(const float4*)&h0[3][k];
      a0 += (x0.x * wA + x0.y * wB) + (x0.z * wC + x0.w * wD);
      a1 += (x1.x * wA + x1.y * wB) + (x1.z * wC + x1.w * wD);
      a2 += (x2.x * wA + x2.y * wB) + (x2.z * wC + x2.w * wD);
      a3 += (x3.x * wA + x3.y * wB) + (x3.z * wC + x3.w * wD);
    }
    h1[0][t] = a0 > 0.f ? a0 : 0.01f * a0;
    h1[1][t] = a1 > 0.f ? a1 : 0.01f * a1;
    h1[2][t] = a2 > 0.f ? a2 : 0.01f * a2;
    h1[3][t] = a3 > 0.f ? a3 : 0.01f * a3;
  }
  __syncthreads();
  {
    const int hh = t & 15, r = (t >> 4) & 3, q = t >> 6;
    const int k0 = q * 64;
    float acc = 0.f;
    for (int k = k0; k < k0 + 64; ++k)
      acc += h1[r][k] * w2[k * 16 + hh];
    pr[q][r][hh] = acc;
  }
  __syncthreads();
  if (t < 64) {
    const int hh = t & 15, r = t >> 4;
    const int p = p0 + r;
    if (p < 3969)
      tbl[hh * 3969 + p] =
          (b2[hh] + ((pr[0][r][hh] + pr[1][r][hh]) + (pr[2][r][hh] + pr[3][r][hh]))) * INVLN2;
  }
}

// ---------------- per-q-row windowed bias max (separable 32x32 sliding max) ----------
__global__ void k_wmax(const float* __restrict__ tbl, float* __restrict__ M2) {
  __shared__ float T[3969];
  __shared__ float R[63 * 32];
  const int h = blockIdx.x, tid = threadIdx.x;
  for (int i = tid; i < 3969; i += 256) T[i] = tbl[h * 3969 + i];
  __syncthreads();
  for (int idx = tid; idx < 63 * 32; idx += 256) {
    const int dy = idx >> 5, xq = idx & 31;
    float m = -3e38f;
#pragma unroll
    for (int j = 0; j < 32; ++j) m = fmaxf(m, T[dy * 63 + xq + j]);
    R[idx] = m;
  }
  __syncthreads();
  for (int idx = tid; idx < 1024; idx += 256) {
    const int yq = idx >> 5, xq = idx & 31;
    float m = -3e38f;
#pragma unroll
    for (int j = 0; j < 32; ++j) m = fmaxf(m, R[(yq + j) * 32 + xq]);
    M2[h * 1024 + idx] = m;
  }
}

// ---------------- bf16 GEMM v11: BN=64 for BOTH modes -> 48 KB LDS, 3 blocks/CU ------
// v11 vs v10: QKV tile shrinks 128x128 -> 128x64 (grid 512->1536 blocks). R12 evidence:
// the 1->3 blocks/CU change on out-proj was the biggest single GEMM win (44->~30 us);
// QKV goes 2->3 blocks/CU for the same cross-block latency-hiding mechanism.
template <int MODE>
__global__ __launch_bounds__(512, 6) void k_gemm(
    const void* __restrict__ A0, const void* __restrict__ A1, const void* __restrict__ A2,
    const u16* __restrict__ B0, const u16* __restrict__ B1, const u16* __restrict__ B2,
    const float* __restrict__ c0, const float* __restrict__ c1, const float* __restrict__ c2,
    void* __restrict__ o0, void* __restrict__ o1, void* __restrict__ o2,
    int Mdim, int Ndim, int Kdim) {
  constexpr int BN = 64;       // N-tile (both modes)
  constexpr int NREP = 2;      // n-fragments per wave
  __shared__ u16 sA[2][128 * 64];
  __shared__ u16 sB[2][BN * 64];

  const int nxy = gridDim.x * gridDim.y;
  const int nwg = nxy * gridDim.z;
  int wg = blockIdx.x + gridDim.x * blockIdx.y + nxy * blockIdx.z;
  wg = (wg & 7) * (nwg >> 3) + (wg >> 3);
  const int z = wg / nxy;
  const int rem = wg % nxy;
  const int by = rem / gridDim.x;
  const int bx = rem % gridDim.x;

  const void* Av = (z == 0) ? A0 : (z == 1) ? A1 : A2;
  const u16* Bt  = (z == 0) ? B0 : (z == 1) ? B1 : B2;
  const float* bias = (z == 0) ? c0 : (z == 1) ? c1 : c2;

  const int tid = threadIdx.x, lane = tid & 63, w = tid >> 6;  // w 0..7
  const int wr = w & 3, wc = w >> 2;   // 4 row-groups x 2 col-groups
  const int m0 = by * 128, n0 = bx * BN;

  const int srow = tid >> 3, sslot = tid & 7;
  const int scol = (sslot ^ (srow & 7)) * 8;
  const float* aF = (const float*)Av + (size_t)(m0 + srow) * Kdim + scol;  // MODE 0
  const u16* aB   = (const u16*)Av + (size_t)(m0 + srow) * Kdim + scol;    // MODE 1
  const u16* bBase = Bt + (size_t)(n0 + srow) * Kdim + scol;

  const int qlo = lane & 15, g = lane >> 4;
  const int swz = (qlo & 7) << 3;

#define ALOAD(arr, kt_)                                                          \
  {                                                                              \
    _Pragma("unroll")                                                            \
    for (int i_ = 0; i_ < 2; ++i_) {                                             \
      arr[i_ * 2 + 0] = *(const float4*)(aF + (size_t)(i_ * 64) * Kdim + (kt_));     \
      arr[i_ * 2 + 1] = *(const float4*)(aF + (size_t)(i_ * 64) * Kdim + (kt_) + 4); \
    }                                                                            \
  }

#define AWRITE(buf, arr)                                                         \
  {                                                                              \
    _Pragma("unroll")                                                            \
    for (int i_ = 0; i_ < 2; ++i_) {                                             \
      u32x4 pk;                                                                  \
      pk.x = cvt_pk_bf16(arr[i_ * 2 + 0].x, arr[i_ * 2 + 0].y);                  \
      pk.y = cvt_pk_bf16(arr[i_ * 2 + 0].z, arr[i_ * 2 + 0].w);                  \
      pk.z = cvt_pk_bf16(arr[i_ * 2 + 1].x, arr[i_ * 2 + 1].y);                  \
      pk.w = cvt_pk_bf16(arr[i_ * 2 + 1].z, arr[i_ * 2 + 1].w);                  \
      *(u32x4*)&sA[buf][(i_ * 64 + srow) * 64 + sslot * 8] = pk;                 \
    }                                                                            \
  }

#define BSTAGE(buf, kt_)                                                         \
  {                                                                              \
    gload_lds16(bBase + (size_t)(kt_), &sB[buf][srow * 64 + sslot * 8]);         \
  }

#define AGLOAD(buf, kt_)                                                         \
  {                                                                              \
    _Pragma("unroll")                                                            \
    for (int i_ = 0; i_ < 2; ++i_)                                               \
      gload_lds16(aB + (size_t)(i_ * 64) * Kdim + (kt_),                         \
                  &sA[buf][(i_ * 64 + srow) * 64 + sslot * 8]);                  \
  }

#define MFMA_PHASE(cur)                                                          \
  {                                                                              \
    __builtin_amdgcn_s_setprio(1);                                               \
    _Pragma("unroll")                                                            \
    for (int ks = 0; ks < 2; ++ks) {                                             \
      s16x8 af[2], bf[NREP];                                                     \
      _Pragma("unroll")                                                          \
      for (int m = 0; m < 2; ++m)                                                \
        af[m] = *(const s16x8*)(&sA[cur][(wr * 32 + m * 16 + qlo) * 64 +         \
                                         ((ks * 32 + g * 8) ^ swz)]);            \
      _Pragma("unroll")                                                          \
      for (int n = 0; n < NREP; ++n)                                             \
        bf[n] = *(const s16x8*)(&sB[cur][(wc * (BN / 2) + n * 16 + qlo) * 64 +   \
                                         ((ks * 32 + g * 8) ^ swz)]);            \
      _Pragma("unroll")                                                          \
      for (int m = 0; m < 2; ++m)                                                \
        _Pragma("unroll")                                                        \
        for (int n = 0; n < NREP; ++n)                                           \
          acc[m][n] = MFMA16(af[m], bf[n], acc[m][n]);                           \
    }                                                                            \
    __builtin_amdgcn_s_setprio(0);                                               \
  }

#define CBAR(deep)                                                               \
  {                                                                              \
    if (deep) asm volatile("s_waitcnt vmcnt(4) lgkmcnt(0)" ::: "memory");        \
    else      asm volatile("s_waitcnt vmcnt(0) lgkmcnt(0)" ::: "memory");        \
    __builtin_amdgcn_s_barrier();                                                \
  }

  f32x4 acc[2][NREP] = {};
  const int nt = Kdim >> 6;  // 16

  if (MODE == 0) {
    float4 arA[4], arB[4];  // even tiles -> arA/buf0, odd -> arB/buf1
    ALOAD(arA, 0);
    BSTAGE(0, 0);
    AWRITE(0, arA);
    ALOAD(arB, 64);
    ALOAD(arA, 128);
    asm volatile("s_waitcnt vmcnt(8) lgkmcnt(0)" ::: "memory");  // retire BSTAGE(0)
    __builtin_amdgcn_s_barrier();

#pragma unroll 1
    for (int tt = 0; tt < nt; tt += 2) {
      // even sub-iter: compute tile tt (buf0)
      if (tt + 1 < nt) BSTAGE(1, (tt + 1) * 64);
      MFMA_PHASE(0);
      if (tt + 1 < nt) AWRITE(1, arB);              // arB = tile tt+1 (2 sub-iters old)
      if (tt + 3 < nt) ALOAD(arB, (tt + 3) * 64);   // load-after-write: distance 2
      CBAR(tt + 3 < nt);
      // odd sub-iter: compute tile tt+1 (buf1)
      if (tt + 2 < nt) BSTAGE(0, (tt + 2) * 64);
      MFMA_PHASE(1);
      if (tt + 2 < nt) AWRITE(0, arA);              // arA = tile tt+2 (2 sub-iters old)
      if (tt + 4 < nt) ALOAD(arA, (tt + 4) * 64);
      CBAR(tt + 4 < nt);
    }
  } else {
    AGLOAD(0, 0);
    BSTAGE(0, 0);
    __syncthreads();
    int cur = 0;
    for (int kt = 0; kt < Kdim; kt += 64) {
      if (kt + 64 < Kdim) { AGLOAD(cur ^ 1, kt + 64); BSTAGE(cur ^ 1, kt + 64); }
      MFMA_PHASE(cur);
      __syncthreads();
      cur ^= 1;
    }
  }
#undef ALOAD
#undef AWRITE
#undef BSTAGE
#undef AGLOAD
#undef MFMA_PHASE
#undef CBAR

  if (MODE == 0) {
    u16* out = (u16*)((z == 0) ? o0 : (z == 1) ? o1 : o2);
    if (z < 2) {
      // Q/K: [bh][s][d] layout (attn reads rows of d)
#pragma unroll
      for (int m = 0; m < 2; ++m) {
        const int gm = m0 + wr * 32 + m * 16 + (g << 2);
#pragma unroll
        for (int n = 0; n < NREP; ++n) {
          const int gn = n0 + wc * (BN / 2) + n * 16 + qlo;
          const float bv = bias[gn];
          const int hh = gn >> 6, dd = gn & 63;
#pragma unroll
          for (int r = 0; r < 4; ++r) {
            const int row = gm + r;
            const int batch = row >> 10, ss = row & 1023;
            out[(((size_t)(batch * 16 + hh)) * 1024 + ss) * 64 + dd] = f2bf(acc[m][n][r] + bv);
          }
        }
      }
    } else {
      // V: write TRANSPOSED [bh][d][s] directly
#pragma unroll
      for (int m = 0; m < 2; ++m) {
        const int gm = m0 + wr * 32 + m * 16 + (g << 2);
        const int batch = gm >> 10, ss0 = gm & 1023;
#pragma unroll
        for (int n = 0; n < NREP; ++n) {
          const int gn = n0 + wc * (BN / 2) + n * 16 + qlo;
          const float bv = bias[gn];
          const int hh = gn >> 6, dd = gn & 63;
          ushort4 o4;
          o4.x = f2bf(acc[m][n][0] + bv);
          o4.y = f2bf(acc[m][n][1] + bv);
          o4.z = f2bf(acc[m][n][2] + bv);
          o4.w = f2bf(acc[m][n][3] + bv);
          *(ushort4*)(out + ((size_t)(batch * 16 + hh) * 64 + dd) * 1024 + ss0) = o4;
        }
      }
    }
  } else {
    float* out = (float*)o0;
#pragma unroll
    for (int m = 0; m < 2; ++m) {
      const int gm = m0 + wr * 32 + m * 16 + (g << 2);
#pragma unroll
      for (int n = 0; n < NREP; ++n) {
        const int gn = n0 + wc * (BN / 2) + n * 16 + qlo;
        const float bv = bias[gn];
#pragma unroll
        for (int r = 0; r < 4; ++r)
          out[(size_t)(gm + r) * Ndim + gn] = acc[m][n][r] + bv;
      }
    }
  }
}

// ---------------- flash attention v8: per-m PV, sP halved, 3 blk/CU ----------
__global__ __launch_bounds__(256, 3) void k_attn(
    const u16* __restrict__ Qb,   // [64 bh][1024][64]
    const u16* __restrict__ Kb,   // [64 bh][1024][64]
    const u16* __restrict__ Vt,   // [64 bh][64][1024]
    const float* __restrict__ tbl,// [16][3969] exp2-domain bias
    const float* __restrict__ M2, // [16][1024] per-q-row windowed bias max
    u16* __restrict__ ctx) {      // [4096][1024]
  __shared__ u16 sK[2][64 * 64];
  __shared__ u16 sV[2][64 * 64];
  __shared__ u32 sP[4][16][32];   // per-wave bounce, ONE m at a time (R2 dataflow)
  __shared__ float sTw[2205];

  const int f = blockIdx.x;
  const int nid = (f & 7) * 64 + (f >> 3);
  const int bh = nid >> 3, qblk = nid & 7;
  const int h = bh & 15, b = bh >> 4;
  const int q0 = qblk * 128, yq0 = qblk * 4;

  const int tid = threadIdx.x, lane = tid & 63, w = tid >> 6;
  const int qlo = lane & 15, g = lane >> 4;
  const u16* Qp = Qb + (size_t)bh * (1024 * 64);
  const u16* Kp = Kb + (size_t)bh * (1024 * 64);
  const u16* Vp = Vt + (size_t)bh * (64 * 1024);

  const int srow = lane >> 3, sslot = lane & 7;
  const int scol = ((sslot ^ srow) * 8);
  const int swz = (qlo & 7) << 3;
  u16* const myP = (u16*)&sP[w][0][0];

#define STAGE(buf, kv0_)                                                          \
  {                                                                               \
    _Pragma("unroll")                                                             \
    for (int i_ = 0; i_ < 2; ++i_) {                                              \
      const int row_ = w * 16 + i_ * 8 + srow;                                    \
      gload_lds16(Kp + (size_t)((kv0_) + row_) * 64 + scol,                       \
                  &sK[buf][row_ * 64 + sslot * 8]);                               \
      gload_lds16(Vp + (size_t)row_ * 1024 + (kv0_) + scol,                       \
                  &sV[buf][row_ * 64 + sslot * 8]);                               \
    }                                                                             \
  }

  STAGE(0, 0);

  {
    const float* tblh = tbl + h * 3969 + yq0 * 63;
    for (int i = tid; i < 2205; i += 256) sTw[i] = tblh[i];
  }

  s16x8 qf[2][2];
  int W2i[2];
  float Mq[2];
#pragma unroll
  for (int m = 0; m < 2; ++m) {
    const int qi = q0 + w * 32 + m * 16 + qlo;
#pragma unroll
    for (int ks = 0; ks < 2; ++ks)
      qf[m][ks] = *(const s16x8*)(Qp + (size_t)qi * 64 + ks * 32 + g * 8);
    W2i[m] = (w + 31) * 63 + (m * 16 + qlo) + 31 - g * 4;
    Mq[m] = M2[h * 1024 + (yq0 + w) * 32 + (m * 16 + qlo)];
  }

  f32x4 accO[2][4] = {};
  float lp[2] = {0.f, 0.f};

  __syncthreads();

  int cur = 0;
  for (int t = 0; t < 16; ++t) {
    const int kv0 = t * 64;
    if (t != 15) STAGE(cur ^ 1, kv0 + 64);

    f32x4 sc[2][4] = {};
    __builtin_amdgcn_s_setprio(1);
#pragma unroll
    for (int ks = 0; ks < 2; ++ks) {
      s16x8 kf[4];
#pragma unroll
      for (int n = 0; n < 4; ++n)
        kf[n] = *(const s16x8*)(&sK[cur][(n * 16 + qlo) * 64 + ((ks * 32 + g * 8) ^ swz)]);
#pragma unroll
      for (int m = 0; m < 2; ++m)
#pragma unroll
        for (int n = 0; n < 4; ++n)
          sc[m][n] = MFMA16(kf[n], qf[m][ks], sc[m][n]);
    }
    __builtin_amdgcn_s_setprio(0);

    s16x8 av[2][4];
#pragma unroll
    for (int ks = 0; ks < 2; ++ks)
#pragma unroll
      for (int n = 0; n < 4; ++n)
        av[ks][n] = *(const s16x8*)(&sV[cur][(n * 16 + qlo) * 64 + ((ks * 32 + g * 8) ^ swz)]);

    const int bk = (kv0 >> 5) * 63;
#pragma unroll
    for (int m = 0; m < 2; ++m) {
      const int bofs = W2i[m] - bk;
      const float mq = Mq[m];
      float p[16];
#pragma unroll
      for (int n = 0; n < 4; ++n)
#pragma unroll
        for (int r = 0; r < 4; ++r)
          p[n * 4 + r] = exp2_f(sc[m][n][r] * SC_X_INVLN2 +
                                (sTw[bofs - ((n >> 1) * 63 + (n & 1) * 16 + r)] - mq));
      lp[m] += (((p[0] + p[1]) + (p[2] + p[3])) + ((p[4] + p[5]) + (p[6] + p[7]))) +
               (((p[8] + p[9]) + (p[10] + p[11])) + ((p[12] + p[13]) + (p[14] + p[15])));

      u32* const prow = &sP[w][qlo][0];
      const int dswz = (qlo & 7) << 2;
#pragma unroll
      for (int n = 0; n < 4; ++n) {
        u32x2 pk;
        pk.x = cvt_pk_bf16(p[n * 4 + 0], p[n * 4 + 1]);
        pk.y = cvt_pk_bf16(p[n * 4 + 2], p[n * 4 + 3]);
        *(u32x2*)&prow[(n * 8 + g * 2) ^ dswz] = pk;
      }

      __builtin_amdgcn_s_setprio(1);
#pragma unroll
      for (int ks = 0; ks < 2; ++ks) {
        const s16x8 pf = *(const s16x8*)(myP + qlo * 64 + ((ks * 32 + g * 8) ^ swz));
#pragma unroll
        for (int n = 0; n < 4; ++n)
          accO[m][n] = MFMA16(av[ks][n], pf, accO[m][n]);
      }
      __builtin_amdgcn_s_setprio(0);
    }

    __syncthreads();
    cur ^= 1;
  }

#pragma unroll
  for (int m = 0; m < 2; ++m) {
    float rs = lp[m];
    rs += __shfl_xor(rs, 16);
    rs += __shfl_xor(rs, 32);
    const float inv = 1.0f / rs;
    const int qi = q0 + w * 32 + m * 16 + qlo;
#pragma unroll
    for (int n = 0; n < 4; ++n) {
      ushort4 o4;
      o4.x = f2bf(accO[m][n][0] * inv);
      o4.y = f2bf(accO[m][n][1] * inv);
      o4.z = f2bf(accO[m][n][2] * inv);
      o4.w = f2bf(accO[m][n][3] * inv);
      *(ushort4*)(ctx + ((size_t)(b * 1024 + qi)) * 1024 + h * 64 + n * 16 + g * 4) = o4;
    }
  }
#undef STAGE
}

// ---------------- launch ----------------
extern "C" void kernel_launch(void* const* d_in, const int* in_sizes, int n_in,
                              void* d_out, int out_size, void* d_ws, size_t ws_size,
                              hipStream_t stream) {
  const float* query = (const float*)d_in[0];
  const float* key   = (const float*)d_in[1];
  const float* value = (const float*)d_in[2];
  const float* wq = (const float*)d_in[3];
  const float* bq = (const float*)d_in[4];
  const float* wk = (const float*)d_in[5];
  const float* bk = (const float*)d_in[6];
  const float* wv = (const float*)d_in[7];
  const float* bv = (const float*)d_in[8];
  const float* wo = (const float*)d_in[9];
  const float* bo = (const float*)d_in[10];
  const float* pw0 = (const float*)d_in[11];
  const float* pb0 = (const float*)d_in[12];
  const float* pw1 = (const float*)d_in[13];
  const float* pb1 = (const float*)d_in[14];
  const float* pw2 = (const float*)d_in[15];
  const float* pb2 = (const float*)d_in[16];

  char* ws = (char*)d_ws;
  u16* Wtq = (u16*)(ws + 25165824);
  u16* Wtk = (u16*)(ws + 27262976);
  u16* Wtv = (u16*)(ws + 29360128);
  u16* Wto = (u16*)(ws + 31457280);
  u16* Qb  = (u16*)(ws + 33554432);
  u16* Kb  = (u16*)(ws + 41943040);
  u16* Vtb = (u16*)(ws + 58720256);
  u16* ctx = (u16*)(ws + 67108864);
  float* tbl = (float*)(ws + 75497472);   // 16*3969*4 = 254016 B
  float* M2  = (float*)(ws + 75759616);   // 16*1024*4 = 65536 B

  k_transpose_w<<<dim3(16, 16, 4), 256, 0, stream>>>(wq, wk, wv, wo, Wtq, Wtk, Wtv, Wto);
  k_posbias<<<dim3(993), 256, 0, stream>>>(pw0, pb0, pw1, pb1, pw2, pb2, tbl);
  k_wmax<<<dim3(16), 256, 0, stream>>>(tbl, M2);
  k_gemm<0><<<dim3(16, 32, 3), 512, 0, stream>>>(query, key, value, Wtq, Wtk, Wtv,
                                                 bq, bk, bv, Qb, Kb, Vtb, 4096, 1024, 1024);
  k_attn<<<dim3(512), 256, 0, stream>>>(Qb, Kb, Vtb, tbl, M2, ctx);
  k_gemm<1><<<dim3(16, 32, 1), 512, 0, stream>>>(ctx, ctx, ctx, Wto, Wto, Wto,
                                                 bo, bo, bo, d_out, d_out, d_out, 4096, 1024, 1024);
}

// Round 20
// 128.527 us; speedup vs baseline: 1.0414x; 1.0414x over previous
//
#include <hip/hip_runtime.h>
#include <stdint.h>

typedef unsigned short u16;
typedef unsigned int   u32;
typedef __attribute__((ext_vector_type(4))) float f32x4;
typedef __attribute__((ext_vector_type(8))) short s16x8;
typedef __attribute__((ext_vector_type(2))) u32 u32x2;
typedef __attribute__((ext_vector_type(4))) u32 u32x4;

__device__ __forceinline__ u16 f2bf(float f) {
  u32 u = __builtin_bit_cast(u32, f);
  u = (u + 0x7FFFu + ((u >> 16) & 1u)) >> 16;
  return (u16)u;
}

__device__ __forceinline__ u32 cvt_pk_bf16(float lo, float hi) {
  u32 r;
  asm("v_cvt_pk_bf16_f32 %0, %1, %2" : "=v"(r) : "v"(lo), "v"(hi));
  return r;
}

__device__ __forceinline__ float exp2_f(float x) {
  float r;
  asm("v_exp_f32 %0, %1" : "=v"(r) : "v"(x));
  return r;
}

__device__ __forceinline__ void gload_lds16(const void* g, void* l) {
  __builtin_amdgcn_global_load_lds((const __attribute__((address_space(1))) void*)g,
                                   (__attribute__((address_space(3))) void*)l,
                                   16, 0, 0);
}

#define MFMA16(a, b, c) __builtin_amdgcn_mfma_f32_16x16x32_bf16((a), (b), (c), 0, 0, 0)

#define INVLN2 1.44269504f
#define SC_X_INVLN2 0.18033688f  /* 0.125 * log2(e) */

// ---------------- transpose+cast weights: W[K][N] fp32 -> Wt[N][K] bf16 ----------------
__global__ void k_transpose_w(const float* __restrict__ w0, const float* __restrict__ w1,
                              const float* __restrict__ w2, const float* __restrict__ w3,
                              u16* __restrict__ o0, u16* __restrict__ o1,
                              u16* __restrict__ o2, u16* __restrict__ o3) {
  __shared__ float t[64][65];
  const int z = blockIdx.z;
  const float* w = (z == 0) ? w0 : (z == 1) ? w1 : (z == 2) ? w2 : w3;
  u16* o = (z == 0) ? o0 : (z == 1) ? o1 : (z == 2) ? o2 : o3;
  const int k0 = blockIdx.x * 64;
  const int n0 = blockIdx.y * 64;
  const int tx = threadIdx.x & 63, ty = threadIdx.x >> 6;
#pragma unroll
  for (int i = 0; i < 16; ++i) {
    const int r = ty * 16 + i;
    t[r][tx] = w[(size_t)(k0 + r) * 1024 + n0 + tx];
  }
  __syncthreads();
#pragma unroll
  for (int i = 0; i < 16; ++i) {
    const int r = ty * 16 + i;
    o[(size_t)(n0 + r) * 1024 + k0 + tx] = f2bf(t[tx][r]);
  }
}

// ---------------- position-bias MLP v2 (exp2-domain output) ----------------
__global__ __launch_bounds__(256) void k_posbias(
    const float* __restrict__ w0, const float* __restrict__ b0,
    const float* __restrict__ w1, const float* __restrict__ b1,
    const float* __restrict__ w2, const float* __restrict__ b2,
    float* __restrict__ tbl) {
  __shared__ float h0[4][264];
  __shared__ float h1[4][264];
  __shared__ float pr[4][4][16];
  const int t = threadIdx.x;
  const int p0 = blockIdx.x * 4;
  {
    const float wy = w0[t], wx = w0[256 + t], bb = b0[t];
#pragma unroll
    for (int r = 0; r < 4; ++r) {
      int p = p0 + r; if (p > 3968) p = 3968;
      const float dy = (float)(p / 63 - 31);
      const float dx = (float)(p % 63 - 31);
      const float v = dy * wy + dx * wx + bb;
      h0[r][t] = v > 0.f ? v : 0.01f * v;
    }
  }
  __syncthreads();
  {
    const float bb = b1[t];
    float a0 = bb, a1 = bb, a2 = bb, a3 = bb;
    for (int k = 0; k < 256; k += 4) {
      const float wA = w1[(k + 0) * 256 + t];
      const float wB = w1[(k + 1) * 256 + t];
      const float wC = w1[(k + 2) * 256 + t];
      const float wD = w1[(k + 3) * 256 + t];
      const float4 x0 = *(const float4*)&h0[0][k];
      const float4 x1 = *(const float4*)&h0[1][k];
      const float4 x2 = *(const float4*)&h0[2][k];
      const float4 x3 = *(const float4*)&h0[3][k];
      a0 += (x0.x * wA + x0.y * wB) + (x0.z * wC + x0.w * wD);
      a1 += (x1.x * wA + x1.y * wB) + (x1.z * wC + x1.w * wD);
      a2 += (x2.x * wA + x2.y * wB) + (x2.z * wC + x2.w * wD);
      a3 += (x3.x * wA + x3.y * wB) + (x3.z * wC + x3.w * wD);
    }
    h1[0][t] = a0 > 0.f ? a0 : 0.01f * a0;
    h1[1][t] = a1 > 0.f ? a1 : 0.01f * a1;
    h1[2][t] = a2 > 0.f ? a2 : 0.01f * a2;
    h1[3][t] = a3 > 0.f ? a3 : 0.01f * a3;
  }
  __syncthreads();
  {
    const int hh = t & 15, r = (t >> 4) & 3, q = t >> 6;
    const int k0 = q * 64;
    float acc = 0.f;
    for (int k = k0; k < k0 + 64; ++k)
      acc += h1[r][k] * w2[k * 16 + hh];
    pr[q][r][hh] = acc;
  }
  __syncthreads();
  if (t < 64) {
    const int hh = t & 15, r = t >> 4;
    const int p = p0 + r;
    if (p < 3969)
      tbl[hh * 3969 + p] =
          (b2[hh] + ((pr[0][r][hh] + pr[1][r][hh]) + (pr[2][r][hh] + pr[3][r][hh]))) * INVLN2;
  }
}

// ---------------- per-q-row windowed bias max (separable 32x32 sliding max) ----------
__global__ void k_wmax(const float* __restrict__ tbl, float* __restrict__ M2) {
  __shared__ float T[3969];
  __shared__ float R[63 * 32];
  const int h = blockIdx.x, tid = threadIdx.x;
  for (int i = tid; i < 3969; i += 256) T[i] = tbl[h * 3969 + i];
  __syncthreads();
  for (int idx = tid; idx < 63 * 32; idx += 256) {
    const int dy = idx >> 5, xq = idx & 31;
    float m = -3e38f;
#pragma unroll
    for (int j = 0; j < 32; ++j) m = fmaxf(m, T[dy * 63 + xq + j]);
    R[idx] = m;
  }
  __syncthreads();
  for (int idx = tid; idx < 1024; idx += 256) {
    const int yq = idx >> 5, xq = idx & 31;
    float m = -3e38f;
#pragma unroll
    for (int j = 0; j < 32; ++j) m = fmaxf(m, R[(yq + j) * 32 + xq]);
    M2[h * 1024 + idx] = m;
  }
}

// ---------------- bf16 GEMM v10: fused cast QKV (dist-2 prefetch) + V transposed -----
// MODE 0 (QKV): 128x128, A=fp32 fused-cast, distance-2 reg prefetch, counted barrier.
// MODE 1 (out-proj): 128x64, both operands gload_lds (3 blocks/CU). R17-proven best.
template <int MODE>
__global__ __launch_bounds__(512, 4) void k_gemm(
    const void* __restrict__ A0, const void* __restrict__ A1, const void* __restrict__ A2,
    const u16* __restrict__ B0, const u16* __restrict__ B1, const u16* __restrict__ B2,
    const float* __restrict__ c0, const float* __restrict__ c1, const float* __restrict__ c2,
    void* __restrict__ o0, void* __restrict__ o1, void* __restrict__ o2,
    int Mdim, int Ndim, int Kdim) {
  constexpr int BN = (MODE == 0) ? 128 : 64;   // N-tile
  constexpr int BITER = BN / 64;               // B staging rounds
  constexpr int NREP = BN / 32;                // n-fragments per wave
  __shared__ u16 sA[2][128 * 64];
  __shared__ u16 sB[2][BN * 64];

  const int nxy = gridDim.x * gridDim.y;
  const int nwg = nxy * gridDim.z;
  int wg = blockIdx.x + gridDim.x * blockIdx.y + nxy * blockIdx.z;
  wg = (wg & 7) * (nwg >> 3) + (wg >> 3);
  const int z = wg / nxy;
  const int rem = wg % nxy;
  const int by = rem / gridDim.x;
  const int bx = rem % gridDim.x;

  const void* Av = (z == 0) ? A0 : (z == 1) ? A1 : A2;
  const u16* Bt  = (z == 0) ? B0 : (z == 1) ? B1 : B2;
  const float* bias = (z == 0) ? c0 : (z == 1) ? c1 : c2;

  const int tid = threadIdx.x, lane = tid & 63, w = tid >> 6;  // w 0..7
  const int wr = w & 3, wc = w >> 2;   // 4 row-groups x 2 col-groups
  const int m0 = by * 128, n0 = bx * BN;

  const int srow = tid >> 3, sslot = tid & 7;
  const int scol = (sslot ^ (srow & 7)) * 8;
  const float* aF = (const float*)Av + (size_t)(m0 + srow) * Kdim + scol;  // MODE 0
  const u16* aB   = (const u16*)Av + (size_t)(m0 + srow) * Kdim + scol;    // MODE 1
  const u16* bBase = Bt + (size_t)(n0 + srow) * Kdim + scol;

  const int qlo = lane & 15, g = lane >> 4;
  const int swz = (qlo & 7) << 3;

#define ALOAD(arr, kt_)                                                          \
  {                                                                              \
    _Pragma("unroll")                                                            \
    for (int i_ = 0; i_ < 2; ++i_) {                                             \
      arr[i_ * 2 + 0] = *(const float4*)(aF + (size_t)(i_ * 64) * Kdim + (kt_));     \
      arr[i_ * 2 + 1] = *(const float4*)(aF + (size_t)(i_ * 64) * Kdim + (kt_) + 4); \
    }                                                                            \
  }

#define AWRITE(buf, arr)                                                         \
  {                                                                              \
    _Pragma("unroll")                                                            \
    for (int i_ = 0; i_ < 2; ++i_) {                                             \
      u32x4 pk;                                                                  \
      pk.x = cvt_pk_bf16(arr[i_ * 2 + 0].x, arr[i_ * 2 + 0].y);                  \
      pk.y = cvt_pk_bf16(arr[i_ * 2 + 0].z, arr[i_ * 2 + 0].w);                  \
      pk.z = cvt_pk_bf16(arr[i_ * 2 + 1].x, arr[i_ * 2 + 1].y);                  \
      pk.w = cvt_pk_bf16(arr[i_ * 2 + 1].z, arr[i_ * 2 + 1].w);                  \
      *(u32x4*)&sA[buf][(i_ * 64 + srow) * 64 + sslot * 8] = pk;                 \
    }                                                                            \
  }

#define BSTAGE(buf, kt_)                                                         \
  {                                                                              \
    _Pragma("unroll")                                                            \
    for (int i_ = 0; i_ < BITER; ++i_)                                           \
      gload_lds16(bBase + (size_t)(i_ * 64) * Kdim + (kt_),                      \
                  &sB[buf][(i_ * 64 + srow) * 64 + sslot * 8]);                  \
  }

#define AGLOAD(buf, kt_)                                                         \
  {                                                                              \
    _Pragma("unroll")                                                            \
    for (int i_ = 0; i_ < 2; ++i_)                                               \
      gload_lds16(aB + (size_t)(i_ * 64) * Kdim + (kt_),                         \
                  &sA[buf][(i_ * 64 + srow) * 64 + sslot * 8]);                  \
  }

#define MFMA_PHASE(cur)                                                          \
  {                                                                              \
    __builtin_amdgcn_s_setprio(1);                                               \
    _Pragma("unroll")                                                            \
    for (int ks = 0; ks < 2; ++ks) {                                             \
      s16x8 af[2], bf[NREP];                                                     \
      _Pragma("unroll")                                                          \
      for (int m = 0; m < 2; ++m)                                                \
        af[m] = *(const s16x8*)(&sA[cur][(wr * 32 + m * 16 + qlo) * 64 +         \
                                         ((ks * 32 + g * 8) ^ swz)]);            \
      _Pragma("unroll")                                                          \
      for (int n = 0; n < NREP; ++n)                                             \
        bf[n] = *(const s16x8*)(&sB[cur][(wc * (BN / 2) + n * 16 + qlo) * 64 +   \
                                         ((ks * 32 + g * 8) ^ swz)]);            \
      _Pragma("unroll")                                                          \
      for (int m = 0; m < 2; ++m)                                                \
        _Pragma("unroll")                                                        \
        for (int n = 0; n < NREP; ++n)                                           \
          acc[m][n] = MFMA16(af[m], bf[n], acc[m][n]);                           \
    }                                                                            \
    __builtin_amdgcn_s_setprio(0);                                               \
  }

#define CBAR(deep)                                                               \
  {                                                                              \
    if (deep) asm volatile("s_waitcnt vmcnt(4) lgkmcnt(0)" ::: "memory");        \
    else      asm volatile("s_waitcnt vmcnt(0) lgkmcnt(0)" ::: "memory");        \
    __builtin_amdgcn_s_barrier();                                                \
  }

  f32x4 acc[2][NREP] = {};
  const int nt = Kdim >> 6;  // 16

  if (MODE == 0) {
    float4 arA[4], arB[4];  // even tiles -> arA/buf0, odd -> arB/buf1
    ALOAD(arA, 0);
    BSTAGE(0, 0);
    AWRITE(0, arA);
    ALOAD(arB, 64);
    ALOAD(arA, 128);
    asm volatile("s_waitcnt vmcnt(8) lgkmcnt(0)" ::: "memory");  // retire BSTAGE(0)
    __builtin_amdgcn_s_barrier();

#pragma unroll 1
    for (int tt = 0; tt < nt; tt += 2) {
      // even sub-iter: compute tile tt (buf0)
      if (tt + 1 < nt) BSTAGE(1, (tt + 1) * 64);
      MFMA_PHASE(0);
      if (tt + 1 < nt) AWRITE(1, arB);              // arB = tile tt+1 (2 sub-iters old)
      if (tt + 3 < nt) ALOAD(arB, (tt + 3) * 64);   // load-after-write: distance 2
      CBAR(tt + 3 < nt);
      // odd sub-iter: compute tile tt+1 (buf1)
      if (tt + 2 < nt) BSTAGE(0, (tt + 2) * 64);
      MFMA_PHASE(1);
      if (tt + 2 < nt) AWRITE(0, arA);              // arA = tile tt+2 (2 sub-iters old)
      if (tt + 4 < nt) ALOAD(arA, (tt + 4) * 64);
      CBAR(tt + 4 < nt);
    }
  } else {
    AGLOAD(0, 0);
    BSTAGE(0, 0);
    __syncthreads();
    int cur = 0;
    for (int kt = 0; kt < Kdim; kt += 64) {
      if (kt + 64 < Kdim) { AGLOAD(cur ^ 1, kt + 64); BSTAGE(cur ^ 1, kt + 64); }
      MFMA_PHASE(cur);
      __syncthreads();
      cur ^= 1;
    }
  }
#undef ALOAD
#undef AWRITE
#undef BSTAGE
#undef AGLOAD
#undef MFMA_PHASE
#undef CBAR

  if (MODE == 0) {
    u16* out = (u16*)((z == 0) ? o0 : (z == 1) ? o1 : o2);
    if (z < 2) {
      // Q/K: [bh][s][d] layout (attn reads rows of d)
#pragma unroll
      for (int m = 0; m < 2; ++m) {
        const int gm = m0 + wr * 32 + m * 16 + (g << 2);
#pragma unroll
        for (int n = 0; n < NREP; ++n) {
          const int gn = n0 + wc * (BN / 2) + n * 16 + qlo;
          const float bv = bias[gn];
          const int hh = gn >> 6, dd = gn & 63;
#pragma unroll
          for (int r = 0; r < 4; ++r) {
            const int row = gm + r;
            const int batch = row >> 10, ss = row & 1023;
            out[(((size_t)(batch * 16 + hh)) * 1024 + ss) * 64 + dd] = f2bf(acc[m][n][r] + bv);
          }
        }
      }
    } else {
      // V: write TRANSPOSED [bh][d][s] directly (replaces k_vt).
#pragma unroll
      for (int m = 0; m < 2; ++m) {
        const int gm = m0 + wr * 32 + m * 16 + (g << 2);
        const int batch = gm >> 10, ss0 = gm & 1023;
#pragma unroll
        for (int n = 0; n < NREP; ++n) {
          const int gn = n0 + wc * (BN / 2) + n * 16 + qlo;
          const float bv = bias[gn];
          const int hh = gn >> 6, dd = gn & 63;
          ushort4 o4;
          o4.x = f2bf(acc[m][n][0] + bv);
          o4.y = f2bf(acc[m][n][1] + bv);
          o4.z = f2bf(acc[m][n][2] + bv);
          o4.w = f2bf(acc[m][n][3] + bv);
          *(ushort4*)(out + ((size_t)(batch * 16 + hh) * 64 + dd) * 1024 + ss0) = o4;
        }
      }
    }
  } else {
    float* out = (float*)o0;
#pragma unroll
    for (int m = 0; m < 2; ++m) {
      const int gm = m0 + wr * 32 + m * 16 + (g << 2);
#pragma unroll
      for (int n = 0; n < NREP; ++n) {
        const int gn = n0 + wc * (BN / 2) + n * 16 + qlo;
        const float bv = bias[gn];
#pragma unroll
        for (int r = 0; r < 4; ++r)
          out[(size_t)(gm + r) * Ndim + gn] = acc[m][n][r] + bv;
      }
    }
  }
}

// ---------------- flash attention v7: windowed-max exp2 softmax ----------
__global__ __launch_bounds__(256, 2) void k_attn(
    const u16* __restrict__ Qb,   // [64 bh][1024][64]
    const u16* __restrict__ Kb,   // [64 bh][1024][64]
    const u16* __restrict__ Vt,   // [64 bh][64][1024]
    const float* __restrict__ tbl,// [16][3969] exp2-domain bias
    const float* __restrict__ M2, // [16][1024] per-q-row windowed bias max
    u16* __restrict__ ctx) {      // [4096][1024]
  __shared__ u16 sK[2][64 * 64];
  __shared__ u16 sV[2][64 * 64];
  __shared__ u32 sP[4][2][16][32];
  __shared__ float sTw[2205];

  const int f = blockIdx.x;
  const int nid = (f & 7) * 64 + (f >> 3);
  const int bh = nid >> 3, qblk = nid & 7;
  const int h = bh & 15, b = bh >> 4;
  const int q0 = qblk * 128, yq0 = qblk * 4;

  const int tid = threadIdx.x, lane = tid & 63, w = tid >> 6;
  const int qlo = lane & 15, g = lane >> 4;
  const u16* Qp = Qb + (size_t)bh * (1024 * 64);
  const u16* Kp = Kb + (size_t)bh * (1024 * 64);
  const u16* Vp = Vt + (size_t)bh * (64 * 1024);

  const int srow = lane >> 3, sslot = lane & 7;
  const int scol = ((sslot ^ srow) * 8);
  const int swz = (qlo & 7) << 3;

#define STAGE(buf, kv0_)                                                          \
  {                                                                               \
    _Pragma("unroll")                                                             \
    for (int i_ = 0; i_ < 2; ++i_) {                                              \
      const int row_ = w * 16 + i_ * 8 + srow;                                    \
      gload_lds16(Kp + (size_t)((kv0_) + row_) * 64 + scol,                       \
                  &sK[buf][row_ * 64 + sslot * 8]);                               \
      gload_lds16(Vp + (size_t)row_ * 1024 + (kv0_) + scol,                       \
                  &sV[buf][row_ * 64 + sslot * 8]);                               \
    }                                                                             \
  }

  STAGE(0, 0);

  {
    const float* tblh = tbl + h * 3969 + yq0 * 63;
    for (int i = tid; i < 2205; i += 256) sTw[i] = tblh[i];
  }

  s16x8 qf[2][2];
  int W2i[2];
  float Mq[2];
#pragma unroll
  for (int m = 0; m < 2; ++m) {
    const int qi = q0 + w * 32 + m * 16 + qlo;
#pragma unroll
    for (int ks = 0; ks < 2; ++ks)
      qf[m][ks] = *(const s16x8*)(Qp + (size_t)qi * 64 + ks * 32 + g * 8);
    W2i[m] = (w + 31) * 63 + (m * 16 + qlo) + 31 - g * 4;
    Mq[m] = M2[h * 1024 + (yq0 + w) * 32 + (m * 16 + qlo)];
  }

  f32x4 accO[2][4] = {};
  float lp[2] = {0.f, 0.f};

  __syncthreads();

  int cur = 0;
  for (int t = 0; t < 16; ++t) {
    const int kv0 = t * 64;
    if (t != 15) STAGE(cur ^ 1, kv0 + 64);

    f32x4 sc[2][4] = {};
    __builtin_amdgcn_s_setprio(1);
#pragma unroll
    for (int ks = 0; ks < 2; ++ks) {
      s16x8 kf[4];
#pragma unroll
      for (int n = 0; n < 4; ++n)
        kf[n] = *(const s16x8*)(&sK[cur][(n * 16 + qlo) * 64 + ((ks * 32 + g * 8) ^ swz)]);
#pragma unroll
      for (int m = 0; m < 2; ++m)
#pragma unroll
        for (int n = 0; n < 4; ++n)
          sc[m][n] = MFMA16(kf[n], qf[m][ks], sc[m][n]);
    }
    __builtin_amdgcn_s_setprio(0);

    const int bk = (kv0 >> 5) * 63;
#pragma unroll
    for (int m = 0; m < 2; ++m) {
      const int bofs = W2i[m] - bk;
      const float mq = Mq[m];
      float p[16];
#pragma unroll
      for (int n = 0; n < 4; ++n)
#pragma unroll
        for (int r = 0; r < 4; ++r)
          p[n * 4 + r] = exp2_f(sc[m][n][r] * SC_X_INVLN2 +
                                (sTw[bofs - ((n >> 1) * 63 + (n & 1) * 16 + r)] - mq));
      lp[m] += (((p[0] + p[1]) + (p[2] + p[3])) + ((p[4] + p[5]) + (p[6] + p[7]))) +
               (((p[8] + p[9]) + (p[10] + p[11])) + ((p[12] + p[13]) + (p[14] + p[15])));

      u32* const prow = &sP[w][m][qlo][0];
      const int dswz = (qlo & 7) << 2;
#pragma unroll
      for (int n = 0; n < 4; ++n) {
        u32x2 pk;
        pk.x = cvt_pk_bf16(p[n * 4 + 0], p[n * 4 + 1]);
        pk.y = cvt_pk_bf16(p[n * 4 + 2], p[n * 4 + 3]);
        *(u32x2*)&prow[(n * 8 + g * 2) ^ dswz] = pk;
      }
    }

    __builtin_amdgcn_s_setprio(1);
#pragma unroll
    for (int ks = 0; ks < 2; ++ks) {
      s16x8 av[4];
#pragma unroll
      for (int n = 0; n < 4; ++n)
        av[n] = *(const s16x8*)(&sV[cur][(n * 16 + qlo) * 64 + ((ks * 32 + g * 8) ^ swz)]);
#pragma unroll
      for (int m = 0; m < 2; ++m) {
        const u16* myPm = (const u16*)&sP[w][m][0][0];
        const s16x8 pf = *(const s16x8*)(myPm + qlo * 64 + ((ks * 32 + g * 8) ^ swz));
#pragma unroll
        for (int n = 0; n < 4; ++n)
          accO[m][n] = MFMA16(av[n], pf, accO[m][n]);
      }
    }
    __builtin_amdgcn_s_setprio(0);

    __syncthreads();
    cur ^= 1;
  }

#pragma unroll
  for (int m = 0; m < 2; ++m) {
    float rs = lp[m];
    rs += __shfl_xor(rs, 16);
    rs += __shfl_xor(rs, 32);
    const float inv = 1.0f / rs;
    const int qi = q0 + w * 32 + m * 16 + qlo;
#pragma unroll
    for (int n = 0; n < 4; ++n) {
      ushort4 o4;
      o4.x = f2bf(accO[m][n][0] * inv);
      o4.y = f2bf(accO[m][n][1] * inv);
      o4.z = f2bf(accO[m][n][2] * inv);
      o4.w = f2bf(accO[m][n][3] * inv);
      *(ushort4*)(ctx + ((size_t)(b * 1024 + qi)) * 1024 + h * 64 + n * 16 + g * 4) = o4;
    }
  }
#undef STAGE
}

// ---------------- launch ----------------
extern "C" void kernel_launch(void* const* d_in, const int* in_sizes, int n_in,
                              void* d_out, int out_size, void* d_ws, size_t ws_size,
                              hipStream_t stream) {
  const float* query = (const float*)d_in[0];
  const float* key   = (const float*)d_in[1];
  const float* value = (const float*)d_in[2];
  const float* wq = (const float*)d_in[3];
  const float* bq = (const float*)d_in[4];
  const float* wk = (const float*)d_in[5];
  const float* bk = (const float*)d_in[6];
  const float* wv = (const float*)d_in[7];
  const float* bv = (const float*)d_in[8];
  const float* wo = (const float*)d_in[9];
  const float* bo = (const float*)d_in[10];
  const float* pw0 = (const float*)d_in[11];
  const float* pb0 = (const float*)d_in[12];
  const float* pw1 = (const float*)d_in[13];
  const float* pb1 = (const float*)d_in[14];
  const float* pw2 = (const float*)d_in[15];
  const float* pb2 = (const float*)d_in[16];

  char* ws = (char*)d_ws;
  u16* Wtq = (u16*)(ws + 25165824);
  u16* Wtk = (u16*)(ws + 27262976);
  u16* Wtv = (u16*)(ws + 29360128);
  u16* Wto = (u16*)(ws + 31457280);
  u16* Qb  = (u16*)(ws + 33554432);
  u16* Kb  = (u16*)(ws + 41943040);
  u16* Vtb = (u16*)(ws + 58720256);
  u16* ctx = (u16*)(ws + 67108864);
  float* tbl = (float*)(ws + 75497472);   // 16*3969*4 = 254016 B
  float* M2  = (float*)(ws + 75759616);   // 16*1024*4 = 65536 B

  k_transpose_w<<<dim3(16, 16, 4), 256, 0, stream>>>(wq, wk, wv, wo, Wtq, Wtk, Wtv, Wto);
  k_posbias<<<dim3(993), 256, 0, stream>>>(pw0, pb0, pw1, pb1, pw2, pb2, tbl);
  k_wmax<<<dim3(16), 256, 0, stream>>>(tbl, M2);
  k_gemm<0><<<dim3(8, 32, 3), 512, 0, stream>>>(query, key, value, Wtq, Wtk, Wtv,
                                                bq, bk, bv, Qb, Kb, Vtb, 4096, 1024, 1024);
  k_attn<<<dim3(512), 256, 0, stream>>>(Qb, Kb, Vtb, tbl, M2, ctx);
  k_gemm<1><<<dim3(16, 32, 1), 512, 0, stream>>>(ctx, ctx, ctx, Wto, Wto, Wto,
                                                 bo, bo, bo, d_out, d_out, d_out, 4096, 1024, 1024);
}

// Round 21
// 125.433 us; speedup vs baseline: 1.0671x; 1.0247x over previous
//
#include <hip/hip_runtime.h>
#include <stdint.h>

typedef unsigned short u16;
typedef unsigned int   u32;
typedef __attribute__((ext_vector_type(4))) float f32x4;
typedef __attribute__((ext_vector_type(8))) short s16x8;
typedef __attribute__((ext_vector_type(2))) u32 u32x2;
typedef __attribute__((ext_vector_type(4))) u32 u32x4;

__device__ __forceinline__ u16 f2bf(float f) {
  u32 u = __builtin_bit_cast(u32, f);
  u = (u + 0x7FFFu + ((u >> 16) & 1u)) >> 16;
  return (u16)u;
}

__device__ __forceinline__ u32 cvt_pk_bf16(float lo, float hi) {
  u32 r;
  asm("v_cvt_pk_bf16_f32 %0, %1, %2" : "=v"(r) : "v"(lo), "v"(hi));
  return r;
}

__device__ __forceinline__ float exp2_f(float x) {
  float r;
  asm("v_exp_f32 %0, %1" : "=v"(r) : "v"(x));
  return r;
}

__device__ __forceinline__ void gload_lds16(const void* g, void* l) {
  __builtin_amdgcn_global_load_lds((const __attribute__((address_space(1))) void*)g,
                                   (__attribute__((address_space(3))) void*)l,
                                   16, 0, 0);
}

#define MFMA16(a, b, c) __builtin_amdgcn_mfma_f32_16x16x32_bf16((a), (b), (c), 0, 0, 0)

#define INVLN2 1.44269504f
#define SC_X_INVLN2 0.18033688f  /* 0.125 * log2(e) */

// ---------------- fused prep: weight transpose+cast (blocks 0..1023) ------------------
//                  + position-bias MLP      (blocks 1024..2016)
// The two workloads are independent; fusing them removes one launch boundary and lets
// them co-schedule across CUs. Bodies are verbatim from the proven separate kernels.
__global__ __launch_bounds__(256) void k_prep(
    const float* __restrict__ w0f, const float* __restrict__ w1f,
    const float* __restrict__ w2f, const float* __restrict__ w3f,
    u16* __restrict__ o0, u16* __restrict__ o1,
    u16* __restrict__ o2, u16* __restrict__ o3,
    const float* __restrict__ pw0, const float* __restrict__ pb0,
    const float* __restrict__ pw1, const float* __restrict__ pb1,
    const float* __restrict__ pw2, const float* __restrict__ pb2,
    float* __restrict__ tbl) {
  const int bid = blockIdx.x;
  const int t = threadIdx.x;
  if (bid < 1024) {
    // ---- weight transpose: W[K][N] fp32 -> Wt[N][K] bf16 ----
    __shared__ float tt[64][65];
    const int z = bid >> 8;
    const float* w = (z == 0) ? w0f : (z == 1) ? w1f : (z == 2) ? w2f : w3f;
    u16* o = (z == 0) ? o0 : (z == 1) ? o1 : (z == 2) ? o2 : o3;
    const int k0 = (bid & 15) * 64;
    const int n0 = ((bid >> 4) & 15) * 64;
    const int tx = t & 63, ty = t >> 6;
#pragma unroll
    for (int i = 0; i < 16; ++i) {
      const int r = ty * 16 + i;
      tt[r][tx] = w[(size_t)(k0 + r) * 1024 + n0 + tx];
    }
    __syncthreads();
#pragma unroll
    for (int i = 0; i < 16; ++i) {
      const int r = ty * 16 + i;
      o[(size_t)(n0 + r) * 1024 + k0 + tx] = f2bf(tt[tx][r]);
    }
  } else {
    // ---- position-bias MLP (exp2-domain output) ----
    __shared__ float h0[4][264];
    __shared__ float h1[4][264];
    __shared__ float pr[4][4][16];
    const int p0 = (bid - 1024) * 4;
    {
      const float wy = pw0[t], wx = pw0[256 + t], bb = pb0[t];
#pragma unroll
      for (int r = 0; r < 4; ++r) {
        int p = p0 + r; if (p > 3968) p = 3968;
        const float dy = (float)(p / 63 - 31);
        const float dx = (float)(p % 63 - 31);
        const float v = dy * wy + dx * wx + bb;
        h0[r][t] = v > 0.f ? v : 0.01f * v;
      }
    }
    __syncthreads();
    {
      const float bb = pb1[t];
      float a0 = bb, a1 = bb, a2 = bb, a3 = bb;
      for (int k = 0; k < 256; k += 4) {
        const float wA = pw1[(k + 0) * 256 + t];
        const float wB = pw1[(k + 1) * 256 + t];
        const float wC = pw1[(k + 2) * 256 + t];
        const float wD = pw1[(k + 3) * 256 + t];
        const float4 x0 = *(const float4*)&h0[0][k];
        const float4 x1 = *(const float4*)&h0[1][k];
        const float4 x2 = *(const float4*)&h0[2][k];
        const float4 x3 = *(const float4*)&h0[3][k];
        a0 += (x0.x * wA + x0.y * wB) + (x0.z * wC + x0.w * wD);
        a1 += (x1.x * wA + x1.y * wB) + (x1.z * wC + x1.w * wD);
        a2 += (x2.x * wA + x2.y * wB) + (x2.z * wC + x2.w * wD);
        a3 += (x3.x * wA + x3.y * wB) + (x3.z * wC + x3.w * wD);
      }
      h1[0][t] = a0 > 0.f ? a0 : 0.01f * a0;
      h1[1][t] = a1 > 0.f ? a1 : 0.01f * a1;
      h1[2][t] = a2 > 0.f ? a2 : 0.01f * a2;
      h1[3][t] = a3 > 0.f ? a3 : 0.01f * a3;
    }
    __syncthreads();
    {
      const int hh = t & 15, r = (t >> 4) & 3, q = t >> 6;
      const int k0 = q * 64;
      float acc = 0.f;
      for (int k = k0; k < k0 + 64; ++k)
        acc += h1[r][k] * pw2[k * 16 + hh];
      pr[q][r][hh] = acc;
    }
    __syncthreads();
    if (t < 64) {
      const int hh = t & 15, r = t >> 4;
      const int p = p0 + r;
      if (p < 3969)
        tbl[hh * 3969 + p] =
            (pb2[hh] + ((pr[0][r][hh] + pr[1][r][hh]) + (pr[2][r][hh] + pr[3][r][hh]))) * INVLN2;
    }
  }
}

// ---------------- per-q-row windowed bias max (separable 32x32 sliding max) ----------
__global__ void k_wmax(const float* __restrict__ tbl, float* __restrict__ M2) {
  __shared__ float T[3969];
  __shared__ float R[63 * 32];
  const int h = blockIdx.x, tid = threadIdx.x;
  for (int i = tid; i < 3969; i += 256) T[i] = tbl[h * 3969 + i];
  __syncthreads();
  for (int idx = tid; idx < 63 * 32; idx += 256) {
    const int dy = idx >> 5, xq = idx & 31;
    float m = -3e38f;
#pragma unroll
    for (int j = 0; j < 32; ++j) m = fmaxf(m, T[dy * 63 + xq + j]);
    R[idx] = m;
  }
  __syncthreads();
  for (int idx = tid; idx < 1024; idx += 256) {
    const int yq = idx >> 5, xq = idx & 31;
    float m = -3e38f;
#pragma unroll
    for (int j = 0; j < 32; ++j) m = fmaxf(m, R[(yq + j) * 32 + xq]);
    M2[h * 1024 + idx] = m;
  }
}

// ---------------- bf16 GEMM v10: fused cast QKV (dist-2 prefetch) + V transposed -----
// MODE 0 (QKV): 128x128, A=fp32 fused-cast, distance-2 reg prefetch, counted barrier.
// MODE 1 (out-proj): 128x64, both operands gload_lds (3 blocks/CU). R17-proven best.
template <int MODE>
__global__ __launch_bounds__(512, 4) void k_gemm(
    const void* __restrict__ A0, const void* __restrict__ A1, const void* __restrict__ A2,
    const u16* __restrict__ B0, const u16* __restrict__ B1, const u16* __restrict__ B2,
    const float* __restrict__ c0, const float* __restrict__ c1, const float* __restrict__ c2,
    void* __restrict__ o0, void* __restrict__ o1, void* __restrict__ o2,
    int Mdim, int Ndim, int Kdim) {
  constexpr int BN = (MODE == 0) ? 128 : 64;   // N-tile
  constexpr int BITER = BN / 64;               // B staging rounds
  constexpr int NREP = BN / 32;                // n-fragments per wave
  __shared__ u16 sA[2][128 * 64];
  __shared__ u16 sB[2][BN * 64];

  const int nxy = gridDim.x * gridDim.y;
  const int nwg = nxy * gridDim.z;
  int wg = blockIdx.x + gridDim.x * blockIdx.y + nxy * blockIdx.z;
  wg = (wg & 7) * (nwg >> 3) + (wg >> 3);
  const int z = wg / nxy;
  const int rem = wg % nxy;
  const int by = rem / gridDim.x;
  const int bx = rem % gridDim.x;

  const void* Av = (z == 0) ? A0 : (z == 1) ? A1 : A2;
  const u16* Bt  = (z == 0) ? B0 : (z == 1) ? B1 : B2;
  const float* bias = (z == 0) ? c0 : (z == 1) ? c1 : c2;

  const int tid = threadIdx.x, lane = tid & 63, w = tid >> 6;  // w 0..7
  const int wr = w & 3, wc = w >> 2;   // 4 row-groups x 2 col-groups
  const int m0 = by * 128, n0 = bx * BN;

  const int srow = tid >> 3, sslot = tid & 7;
  const int scol = (sslot ^ (srow & 7)) * 8;
  const float* aF = (const float*)Av + (size_t)(m0 + srow) * Kdim + scol;  // MODE 0
  const u16* aB   = (const u16*)Av + (size_t)(m0 + srow) * Kdim + scol;    // MODE 1
  const u16* bBase = Bt + (size_t)(n0 + srow) * Kdim + scol;

  const int qlo = lane & 15, g = lane >> 4;
  const int swz = (qlo & 7) << 3;

#define ALOAD(arr, kt_)                                                          \
  {                                                                              \
    _Pragma("unroll")                                                            \
    for (int i_ = 0; i_ < 2; ++i_) {                                             \
      arr[i_ * 2 + 0] = *(const float4*)(aF + (size_t)(i_ * 64) * Kdim + (kt_));     \
      arr[i_ * 2 + 1] = *(const float4*)(aF + (size_t)(i_ * 64) * Kdim + (kt_) + 4); \
    }                                                                            \
  }

#define AWRITE(buf, arr)                                                         \
  {                                                                              \
    _Pragma("unroll")                                                            \
    for (int i_ = 0; i_ < 2; ++i_) {                                             \
      u32x4 pk;                                                                  \
      pk.x = cvt_pk_bf16(arr[i_ * 2 + 0].x, arr[i_ * 2 + 0].y);                  \
      pk.y = cvt_pk_bf16(arr[i_ * 2 + 0].z, arr[i_ * 2 + 0].w);                  \
      pk.z = cvt_pk_bf16(arr[i_ * 2 + 1].x, arr[i_ * 2 + 1].y);                  \
      pk.w = cvt_pk_bf16(arr[i_ * 2 + 1].z, arr[i_ * 2 + 1].w);                  \
      *(u32x4*)&sA[buf][(i_ * 64 + srow) * 64 + sslot * 8] = pk;                 \
    }                                                                            \
  }

#define BSTAGE(buf, kt_)                                                         \
  {                                                                              \
    _Pragma("unroll")                                                            \
    for (int i_ = 0; i_ < BITER; ++i_)                                           \
      gload_lds16(bBase + (size_t)(i_ * 64) * Kdim + (kt_),                      \
                  &sB[buf][(i_ * 64 + srow) * 64 + sslot * 8]);                  \
  }

#define AGLOAD(buf, kt_)                                                         \
  {                                                                              \
    _Pragma("unroll")                                                            \
    for (int i_ = 0; i_ < 2; ++i_)                                               \
      gload_lds16(aB + (size_t)(i_ * 64) * Kdim + (kt_),                         \
                  &sA[buf][(i_ * 64 + srow) * 64 + sslot * 8]);                  \
  }

#define MFMA_PHASE(cur)                                                          \
  {                                                                              \
    __builtin_amdgcn_s_setprio(1);                                               \
    _Pragma("unroll")                                                            \
    for (int ks = 0; ks < 2; ++ks) {                                             \
      s16x8 af[2], bf[NREP];                                                     \
      _Pragma("unroll")                                                          \
      for (int m = 0; m < 2; ++m)                                                \
        af[m] = *(const s16x8*)(&sA[cur][(wr * 32 + m * 16 + qlo) * 64 +         \
                                         ((ks * 32 + g * 8) ^ swz)]);            \
      _Pragma("unroll")                                                          \
      for (int n = 0; n < NREP; ++n)                                             \
        bf[n] = *(const s16x8*)(&sB[cur][(wc * (BN / 2) + n * 16 + qlo) * 64 +   \
                                         ((ks * 32 + g * 8) ^ swz)]);            \
      _Pragma("unroll")                                                          \
      for (int m = 0; m < 2; ++m)                                                \
        _Pragma("unroll")                                                        \
        for (int n = 0; n < NREP; ++n)                                           \
          acc[m][n] = MFMA16(af[m], bf[n], acc[m][n]);                           \
    }                                                                            \
    __builtin_amdgcn_s_setprio(0);                                               \
  }

#define CBAR(deep)                                                               \
  {                                                                              \
    if (deep) asm volatile("s_waitcnt vmcnt(4) lgkmcnt(0)" ::: "memory");        \
    else      asm volatile("s_waitcnt vmcnt(0) lgkmcnt(0)" ::: "memory");        \
    __builtin_amdgcn_s_barrier();                                                \
  }

  f32x4 acc[2][NREP] = {};
  const int nt = Kdim >> 6;  // 16

  if (MODE == 0) {
    float4 arA[4], arB[4];  // even tiles -> arA/buf0, odd -> arB/buf1
    ALOAD(arA, 0);
    BSTAGE(0, 0);
    AWRITE(0, arA);
    ALOAD(arB, 64);
    ALOAD(arA, 128);
    asm volatile("s_waitcnt vmcnt(8) lgkmcnt(0)" ::: "memory");  // retire BSTAGE(0)
    __builtin_amdgcn_s_barrier();

#pragma unroll 1
    for (int tt = 0; tt < nt; tt += 2) {
      // even sub-iter: compute tile tt (buf0)
      if (tt + 1 < nt) BSTAGE(1, (tt + 1) * 64);
      MFMA_PHASE(0);
      if (tt + 1 < nt) AWRITE(1, arB);              // arB = tile tt+1 (2 sub-iters old)
      if (tt + 3 < nt) ALOAD(arB, (tt + 3) * 64);   // load-after-write: distance 2
      CBAR(tt + 3 < nt);
      // odd sub-iter: compute tile tt+1 (buf1)
      if (tt + 2 < nt) BSTAGE(0, (tt + 2) * 64);
      MFMA_PHASE(1);
      if (tt + 2 < nt) AWRITE(0, arA);              // arA = tile tt+2 (2 sub-iters old)
      if (tt + 4 < nt) ALOAD(arA, (tt + 4) * 64);
      CBAR(tt + 4 < nt);
    }
  } else {
    AGLOAD(0, 0);
    BSTAGE(0, 0);
    __syncthreads();
    int cur = 0;
    for (int kt = 0; kt < Kdim; kt += 64) {
      if (kt + 64 < Kdim) { AGLOAD(cur ^ 1, kt + 64); BSTAGE(cur ^ 1, kt + 64); }
      MFMA_PHASE(cur);
      __syncthreads();
      cur ^= 1;
    }
  }
#undef ALOAD
#undef AWRITE
#undef BSTAGE
#undef AGLOAD
#undef MFMA_PHASE
#undef CBAR

  if (MODE == 0) {
    u16* out = (u16*)((z == 0) ? o0 : (z == 1) ? o1 : o2);
    if (z < 2) {
      // Q/K: [bh][s][d] layout (attn reads rows of d)
#pragma unroll
      for (int m = 0; m < 2; ++m) {
        const int gm = m0 + wr * 32 + m * 16 + (g << 2);
#pragma unroll
        for (int n = 0; n < NREP; ++n) {
          const int gn = n0 + wc * (BN / 2) + n * 16 + qlo;
          const float bv = bias[gn];
          const int hh = gn >> 6, dd = gn & 63;
#pragma unroll
          for (int r = 0; r < 4; ++r) {
            const int row = gm + r;
            const int batch = row >> 10, ss = row & 1023;
            out[(((size_t)(batch * 16 + hh)) * 1024 + ss) * 64 + dd] = f2bf(acc[m][n][r] + bv);
          }
        }
      }
    } else {
      // V: write TRANSPOSED [bh][d][s] directly (replaces k_vt).
#pragma unroll
      for (int m = 0; m < 2; ++m) {
        const int gm = m0 + wr * 32 + m * 16 + (g << 2);
        const int batch = gm >> 10, ss0 = gm & 1023;
#pragma unroll
        for (int n = 0; n < NREP; ++n) {
          const int gn = n0 + wc * (BN / 2) + n * 16 + qlo;
          const float bv = bias[gn];
          const int hh = gn >> 6, dd = gn & 63;
          ushort4 o4;
          o4.x = f2bf(acc[m][n][0] + bv);
          o4.y = f2bf(acc[m][n][1] + bv);
          o4.z = f2bf(acc[m][n][2] + bv);
          o4.w = f2bf(acc[m][n][3] + bv);
          *(ushort4*)(out + ((size_t)(batch * 16 + hh) * 64 + dd) * 1024 + ss0) = o4;
        }
      }
    }
  } else {
    float* out = (float*)o0;
#pragma unroll
    for (int m = 0; m < 2; ++m) {
      const int gm = m0 + wr * 32 + m * 16 + (g << 2);
#pragma unroll
      for (int n = 0; n < NREP; ++n) {
        const int gn = n0 + wc * (BN / 2) + n * 16 + qlo;
        const float bv = bias[gn];
#pragma unroll
        for (int r = 0; r < 4; ++r)
          out[(size_t)(gm + r) * Ndim + gn] = acc[m][n][r] + bv;
      }
    }
  }
}

// ---------------- flash attention v7: windowed-max exp2 softmax ----------
__global__ __launch_bounds__(256, 2) void k_attn(
    const u16* __restrict__ Qb,   // [64 bh][1024][64]
    const u16* __restrict__ Kb,   // [64 bh][1024][64]
    const u16* __restrict__ Vt,   // [64 bh][64][1024]
    const float* __restrict__ tbl,// [16][3969] exp2-domain bias
    const float* __restrict__ M2, // [16][1024] per-q-row windowed bias max
    u16* __restrict__ ctx) {      // [4096][1024]
  __shared__ u16 sK[2][64 * 64];
  __shared__ u16 sV[2][64 * 64];
  __shared__ u32 sP[4][2][16][32];
  __shared__ float sTw[2205];

  const int f = blockIdx.x;
  const int nid = (f & 7) * 64 + (f >> 3);
  const int bh = nid >> 3, qblk = nid & 7;
  const int h = bh & 15, b = bh >> 4;
  const int q0 = qblk * 128, yq0 = qblk * 4;

  const int tid = threadIdx.x, lane = tid & 63, w = tid >> 6;
  const int qlo = lane & 15, g = lane >> 4;
  const u16* Qp = Qb + (size_t)bh * (1024 * 64);
  const u16* Kp = Kb + (size_t)bh * (1024 * 64);
  const u16* Vp = Vt + (size_t)bh * (64 * 1024);

  const int srow = lane >> 3, sslot = lane & 7;
  const int scol = ((sslot ^ srow) * 8);
  const int swz = (qlo & 7) << 3;

#define STAGE(buf, kv0_)                                                          \
  {                                                                               \
    _Pragma("unroll")                                                             \
    for (int i_ = 0; i_ < 2; ++i_) {                                              \
      const int row_ = w * 16 + i_ * 8 + srow;                                    \
      gload_lds16(Kp + (size_t)((kv0_) + row_) * 64 + scol,                       \
                  &sK[buf][row_ * 64 + sslot * 8]);                               \
      gload_lds16(Vp + (size_t)row_ * 1024 + (kv0_) + scol,                       \
                  &sV[buf][row_ * 64 + sslot * 8]);                               \
    }                                                                             \
  }

  STAGE(0, 0);

  {
    const float* tblh = tbl + h * 3969 + yq0 * 63;
    for (int i = tid; i < 2205; i += 256) sTw[i] = tblh[i];
  }

  s16x8 qf[2][2];
  int W2i[2];
  float Mq[2];
#pragma unroll
  for (int m = 0; m < 2; ++m) {
    const int qi = q0 + w * 32 + m * 16 + qlo;
#pragma unroll
    for (int ks = 0; ks < 2; ++ks)
      qf[m][ks] = *(const s16x8*)(Qp + (size_t)qi * 64 + ks * 32 + g * 8);
    W2i[m] = (w + 31) * 63 + (m * 16 + qlo) + 31 - g * 4;
    Mq[m] = M2[h * 1024 + (yq0 + w) * 32 + (m * 16 + qlo)];
  }

  f32x4 accO[2][4] = {};
  float lp[2] = {0.f, 0.f};

  __syncthreads();

  int cur = 0;
  for (int t = 0; t < 16; ++t) {
    const int kv0 = t * 64;
    if (t != 15) STAGE(cur ^ 1, kv0 + 64);

    f32x4 sc[2][4] = {};
    __builtin_amdgcn_s_setprio(1);
#pragma unroll
    for (int ks = 0; ks < 2; ++ks) {
      s16x8 kf[4];
#pragma unroll
      for (int n = 0; n < 4; ++n)
        kf[n] = *(const s16x8*)(&sK[cur][(n * 16 + qlo) * 64 + ((ks * 32 + g * 8) ^ swz)]);
#pragma unroll
      for (int m = 0; m < 2; ++m)
#pragma unroll
        for (int n = 0; n < 4; ++n)
          sc[m][n] = MFMA16(kf[n], qf[m][ks], sc[m][n]);
    }
    __builtin_amdgcn_s_setprio(0);

    const int bk = (kv0 >> 5) * 63;
#pragma unroll
    for (int m = 0; m < 2; ++m) {
      const int bofs = W2i[m] - bk;
      const float mq = Mq[m];
      float p[16];
#pragma unroll
      for (int n = 0; n < 4; ++n)
#pragma unroll
        for (int r = 0; r < 4; ++r)
          p[n * 4 + r] = exp2_f(sc[m][n][r] * SC_X_INVLN2 +
                                (sTw[bofs - ((n >> 1) * 63 + (n & 1) * 16 + r)] - mq));
      lp[m] += (((p[0] + p[1]) + (p[2] + p[3])) + ((p[4] + p[5]) + (p[6] + p[7]))) +
               (((p[8] + p[9]) + (p[10] + p[11])) + ((p[12] + p[13]) + (p[14] + p[15])));

      u32* const prow = &sP[w][m][qlo][0];
      const int dswz = (qlo & 7) << 2;
#pragma unroll
      for (int n = 0; n < 4; ++n) {
        u32x2 pk;
        pk.x = cvt_pk_bf16(p[n * 4 + 0], p[n * 4 + 1]);
        pk.y = cvt_pk_bf16(p[n * 4 + 2], p[n * 4 + 3]);
        *(u32x2*)&prow[(n * 8 + g * 2) ^ dswz] = pk;
      }
    }

    __builtin_amdgcn_s_setprio(1);
#pragma unroll
    for (int ks = 0; ks < 2; ++ks) {
      s16x8 av[4];
#pragma unroll
      for (int n = 0; n < 4; ++n)
        av[n] = *(const s16x8*)(&sV[cur][(n * 16 + qlo) * 64 + ((ks * 32 + g * 8) ^ swz)]);
#pragma unroll
      for (int m = 0; m < 2; ++m) {
        const u16* myPm = (const u16*)&sP[w][m][0][0];
        const s16x8 pf = *(const s16x8*)(myPm + qlo * 64 + ((ks * 32 + g * 8) ^ swz));
#pragma unroll
        for (int n = 0; n < 4; ++n)
          accO[m][n] = MFMA16(av[n], pf, accO[m][n]);
      }
    }
    __builtin_amdgcn_s_setprio(0);

    __syncthreads();
    cur ^= 1;
  }

#pragma unroll
  for (int m = 0; m < 2; ++m) {
    float rs = lp[m];
    rs += __shfl_xor(rs, 16);
    rs += __shfl_xor(rs, 32);
    const float inv = 1.0f / rs;
    const int qi = q0 + w * 32 + m * 16 + qlo;
#pragma unroll
    for (int n = 0; n < 4; ++n) {
      ushort4 o4;
      o4.x = f2bf(accO[m][n][0] * inv);
      o4.y = f2bf(accO[m][n][1] * inv);
      o4.z = f2bf(accO[m][n][2] * inv);
      o4.w = f2bf(accO[m][n][3] * inv);
      *(ushort4*)(ctx + ((size_t)(b * 1024 + qi)) * 1024 + h * 64 + n * 16 + g * 4) = o4;
    }
  }
#undef STAGE
}

// ---------------- launch ----------------
extern "C" void kernel_launch(void* const* d_in, const int* in_sizes, int n_in,
                              void* d_out, int out_size, void* d_ws, size_t ws_size,
                              hipStream_t stream) {
  const float* query = (const float*)d_in[0];
  const float* key   = (const float*)d_in[1];
  const float* value = (const float*)d_in[2];
  const float* wq = (const float*)d_in[3];
  const float* bq = (const float*)d_in[4];
  const float* wk = (const float*)d_in[5];
  const float* bk = (const float*)d_in[6];
  const float* wv = (const float*)d_in[7];
  const float* bv = (const float*)d_in[8];
  const float* wo = (const float*)d_in[9];
  const float* bo = (const float*)d_in[10];
  const float* pw0 = (const float*)d_in[11];
  const float* pb0 = (const float*)d_in[12];
  const float* pw1 = (const float*)d_in[13];
  const float* pb1 = (const float*)d_in[14];
  const float* pw2 = (const float*)d_in[15];
  const float* pb2 = (const float*)d_in[16];

  char* ws = (char*)d_ws;
  u16* Wtq = (u16*)(ws + 25165824);
  u16* Wtk = (u16*)(ws + 27262976);
  u16* Wtv = (u16*)(ws + 29360128);
  u16* Wto = (u16*)(ws + 31457280);
  u16* Qb  = (u16*)(ws + 33554432);
  u16* Kb  = (u16*)(ws + 41943040);
  u16* Vtb = (u16*)(ws + 58720256);
  u16* ctx = (u16*)(ws + 67108864);
  float* tbl = (float*)(ws + 75497472);   // 16*3969*4 = 254016 B
  float* M2  = (float*)(ws + 75759616);   // 16*1024*4 = 65536 B

  k_prep<<<dim3(2017), 256, 0, stream>>>(wq, wk, wv, wo, Wtq, Wtk, Wtv, Wto,
                                         pw0, pb0, pw1, pb1, pw2, pb2, tbl);
  k_wmax<<<dim3(16), 256, 0, stream>>>(tbl, M2);
  k_gemm<0><<<dim3(8, 32, 3), 512, 0, stream>>>(query, key, value, Wtq, Wtk, Wtv,
                                                bq, bk, bv, Qb, Kb, Vtb, 4096, 1024, 1024);
  k_attn<<<dim3(512), 256, 0, stream>>>(Qb, Kb, Vtb, tbl, M2, ctx);
  k_gemm<1><<<dim3(16, 32, 1), 512, 0, stream>>>(ctx, ctx, ctx, Wto, Wto, Wto,
                                                 bo, bo, bo, d_out, d_out, d_out, 4096, 1024, 1024);
}